// Round 11
// baseline (230.113 us; speedup 1.0000x reference)
//
#include <hip/hip_runtime.h>
#include <hip/hip_bf16.h>
#include <math.h>

#define S_LEN 2048
#define BATCH 2
#define EDIM 1024
#define NH 16
#define HD 64
#define MTOK (S_LEN * BATCH)   // 4096 tokens
#define SCALE 0.125f           // 64^-0.5
#define EPS 1e-6f

typedef __bf16 bf16x8 __attribute__((ext_vector_type(8)));
typedef __bf16 bf16x4 __attribute__((ext_vector_type(4)));
typedef float f32x4 __attribute__((ext_vector_type(4)));

typedef __attribute__((address_space(3))) void lds_void;
typedef const __attribute__((address_space(1))) void gbl_void;
#define GLOAD_LDS16(g, l) \
    __builtin_amdgcn_global_load_lds((gbl_void*)(g), (lds_void*)(l), 16, 0, 0)

// All bf16 GEMM operand buffers use the "row-rotation" layout: within each
// aligned 64-col block of row m, element at col c is stored at
// (c & ~63) | ((c + (m&7)*8) & 63). GEMM frag reads apply the inverse
// (rot=(lo&7)*8) -> LDS reads are 2-way (free, m136) instead of 16-way.

// ---------------------------------------------------------------------------
// cast_all: x -> xb (rotated), Wq|Wk|Wv -> Wqkvb (rotated), Wo*nw -> Wob
// (rotated, norm_w folded). Also zero-inits the per-token sumsq buffer.
// ---------------------------------------------------------------------------
__global__ __launch_bounds__(256) void cast_all(const float* __restrict__ x,
                                                const float* __restrict__ Wq,
                                                const float* __restrict__ Wk,
                                                const float* __restrict__ Wv,
                                                const float* __restrict__ Wo,
                                                const float* __restrict__ nw,
                                                __bf16* __restrict__ xb,
                                                __bf16* __restrict__ Wqkvb,
                                                __bf16* __restrict__ Wob,
                                                float* __restrict__ sumsq) {
    int gt = blockIdx.x * 256 + threadIdx.x;
    if (gt < 1024) ((float4*)sumsq)[gt] = (float4){0.f, 0.f, 0.f, 0.f};
    int i = gt * 8;

    const float* src;
    __bf16* dstbase;
    int row, c;
    bool isWo = false;
    if (i < (MTOK * EDIM)) {
        src = x + i;
        row = i >> 10; c = i & 1023;
        dstbase = xb + ((size_t)row << 10);
    } else {
        int j = i - MTOK * EDIM;
        int seg = j >> 20;
        int off = j & 0xFFFFF;
        src = ((seg == 0) ? Wq : (seg == 1) ? Wk : (seg == 2) ? Wv : Wo) + off;
        row = off >> 10; c = off & 1023;
        if (seg < 3) { dstbase = Wqkvb + ((size_t)(j >> 10) << 10); }
        else         { dstbase = Wob + ((size_t)row << 10); isWo = true; }
    }
    float4 a = *(const float4*)(src);
    float4 b = *(const float4*)(src + 4);
    if (isWo) {
        float4 na = *(const float4*)(nw + c);
        float4 nb = *(const float4*)(nw + c + 4);
        a.x *= na.x; a.y *= na.y; a.z *= na.z; a.w *= na.w;
        b.x *= nb.x; b.y *= nb.y; b.z *= nb.z; b.w *= nb.w;
    }
    bf16x8 o;
    o[0] = (__bf16)a.x; o[1] = (__bf16)a.y; o[2] = (__bf16)a.z; o[3] = (__bf16)a.w;
    o[4] = (__bf16)b.x; o[5] = (__bf16)b.y; o[6] = (__bf16)b.z; o[7] = (__bf16)b.w;
    int rot = (row & 7) * 8;
    int cp = (c & ~63) | ((c + rot) & 63);
    *(bf16x8*)(dstbase + cp) = o;
}

// ---------------------------------------------------------------------------
// QKV GEMM (unchanged from R10): 256x128 tile, 512 threads, fused RoPE (q,k)
// and chunked wave-private V transpose epilogues.
// ---------------------------------------------------------------------------
__global__ __launch_bounds__(512) void gemm_qkv(const __bf16* __restrict__ A,
                                                const __bf16* __restrict__ W,
                                                const float* __restrict__ bias0,
                                                const float* __restrict__ bias1,
                                                const float* __restrict__ bias2,
                                                __bf16* __restrict__ qb,
                                                __bf16* __restrict__ kb,
                                                __bf16* __restrict__ vT,
                                                const float* __restrict__ cosT,
                                                const float* __restrict__ sinT) {
    __shared__ __bf16 SMEM[256 * 64 + 128 * 64];   // As | Bs, 48 KB
    __bf16* As = SMEM;
    __bf16* Bs = SMEM + 256 * 64;

    const int tid  = threadIdx.x;
    const int w    = tid >> 6;       // 0..7
    const int lane = tid & 63;
    const int quad = lane >> 4;
    const int lo   = lane & 15;
    const int wr   = w >> 1;         // M-wave 0..3
    const int wc   = w & 1;          // N-wave 0..1
    const int m0 = blockIdx.y * 256;
    const int n0 = blockIdx.x * 128;
    const int K = EDIM;

    f32x4 acc[4][4];
#pragma unroll
    for (int i = 0; i < 4; ++i)
#pragma unroll
        for (int j = 0; j < 4; ++j) acc[i][j] = (f32x4){0.f, 0.f, 0.f, 0.f};

    const int srow = (lane >> 3);        // 0..7
    const int scol = (lane & 7) * 8;
    const int rotc = (lo & 7) * 8;       // inverse of the row-rotation

    for (int kt = 0; kt < K; kt += 64) {
        __syncthreads();
#pragma unroll
        for (int i = 0; i < 4; ++i) {
            const int r = i * 64 + w * 8;
            GLOAD_LDS16(A + (size_t)(m0 + r + srow) * K + kt + scol, &As[r * 64]);
        }
#pragma unroll
        for (int i = 0; i < 2; ++i) {
            const int r = i * 64 + w * 8;
            GLOAD_LDS16(W + (size_t)(n0 + r + srow) * K + kt + scol, &Bs[r * 64]);
        }
        __syncthreads();

#pragma unroll
        for (int kk = 0; kk < 2; ++kk) {
            const int cidx = (kk * 32 + quad * 8 + rotc) & 63;
            bf16x8 af[4], bf[4];
#pragma unroll
            for (int t = 0; t < 4; ++t) {
                af[t] = *(const bf16x8*)&As[(wr * 64 + t * 16 + lo) * 64 + cidx];
                bf[t] = *(const bf16x8*)&Bs[(wc * 64 + t * 16 + lo) * 64 + cidx];
            }
#pragma unroll
            for (int mt = 0; mt < 4; ++mt)
#pragma unroll
                for (int nt = 0; nt < 4; ++nt)
                    acc[mt][nt] = __builtin_amdgcn_mfma_f32_16x16x32_bf16(
                        af[mt], bf[nt], acc[mt][nt], 0, 0, 0);
        }
    }

    const int seg = n0 >> 10;
    const int colbase = (n0 & 1023) + wc * 64;

    if (seg < 2) {
        const float* bp = (seg == 0) ? bias0 : bias1;
        __bf16* dstb = (seg == 0) ? qb : kb;
        const int h = colbase >> 6;
        float b0v = bp[colbase + lo];
        float b1v = bp[colbase + 16 + lo];
        float b2v = bp[colbase + 32 + lo];
        float b3v = bp[colbase + 48 + lo];
#pragma unroll
        for (int mt = 0; mt < 4; ++mt) {
#pragma unroll
            for (int r = 0; r < 4; ++r) {
                const int m = m0 + wr * 64 + mt * 16 + quad * 4 + r;
                const int s = m >> 1, bidx = m & 1;
                float x0 = acc[mt][0][r] + b0v;
                float x1 = acc[mt][1][r] + b1v;
                float x2 = acc[mt][2][r] + b2v;
                float x3 = acc[mt][3][r] + b3v;
                const float* ct = cosT + s * 64;
                const float* st = sinT + s * 64;
                float o0 = x0 * ct[lo]      - x2 * st[lo];
                float o1 = x1 * ct[16 + lo] - x3 * st[16 + lo];
                float o2 = x2 * ct[32 + lo] + x0 * st[32 + lo];
                float o3 = x3 * ct[48 + lo] + x1 * st[48 + lo];
                __bf16* row = dstb + ((size_t)(bidx * NH + h) * S_LEN + s) * 64;
                if (seg == 0) {
                    row[lo]      = (__bf16)(o0 * SCALE);
                    row[16 + lo] = (__bf16)(o1 * SCALE);
                    row[32 + lo] = (__bf16)(o2 * SCALE);
                    row[48 + lo] = (__bf16)(o3 * SCALE);
                } else {
                    const int rot = (s & 7) * 8;
                    row[(lo + rot) & 63]      = (__bf16)o0;
                    row[(16 + lo + rot) & 63] = (__bf16)o1;
                    row[(32 + lo + rot) & 63] = (__bf16)o2;
                    row[(48 + lo + rot) & 63] = (__bf16)o3;
                }
            }
        }
    } else {
        __syncthreads();   // all waves done frag-reading As/Bs
        const int h = ((n0 - 2048) >> 6) + wc;
        const int sbase = (m0 >> 1) + wr * 32;
        float bv4[4];
        bv4[0] = bias2[h * 64 + lo];
        bv4[1] = bias2[h * 64 + 16 + lo];
        bv4[2] = bias2[h * 64 + 32 + lo];
        bv4[3] = bias2[h * 64 + 48 + lo];
        __bf16* Treg = SMEM + w * 1088;      // 16 rows x 68
        const int rdrow = lane >> 2;          // 0..15
        const int rdcol = (lane & 3) * 16;    // 0,16,32,48
#pragma unroll
        for (int nt = 0; nt < 4; ++nt) {
#pragma unroll
            for (int mt = 0; mt < 4; ++mt)
#pragma unroll
                for (int r = 0; r < 4; ++r) {
                    const int tl = mt * 16 + quad * 4 + r;
                    const int li = (tl & 1) * 32 + (tl >> 1);
                    Treg[lo * 68 + li] = (__bf16)(acc[mt][nt][r] + bv4[nt]);
                }
            const int d = nt * 16 + rdrow;
            const int rot = (d & 7) * 8;
            const int bidx = rdcol >> 5;
            const int soff = rdcol & 31;
            bf16x8 v0 = *(const bf16x8*)&Treg[rdrow * 68 + rdcol];
            bf16x8 v1 = *(const bf16x8*)&Treg[rdrow * 68 + rdcol + 8];
            __bf16* base = vT + ((size_t)((bidx * NH + h) * 64 + d)) * S_LEN;
            const int s0 = sbase + soff;
            const int s1 = s0 + 8;
            *(bf16x8*)(base + (s0 & ~63) + (((s0 & 63) + rot) & 63)) = v0;
            *(bf16x8*)(base + (s1 & ~63) + (((s1 & 63) + rot) & 63)) = v1;
        }
    }
}

// ---------------------------------------------------------------------------
// Out-proj GEMM (unchanged from R10): folded-RMSNorm epilogue.
// ---------------------------------------------------------------------------
__global__ __launch_bounds__(256) void gemm_out(const __bf16* __restrict__ A,
                                                const __bf16* __restrict__ W,
                                                const float* __restrict__ sumsq,
                                                float* __restrict__ outF) {
    __shared__ __bf16 As[128 * 64];
    __shared__ __bf16 Bs[128 * 64];

    const int tid  = threadIdx.x;
    const int w    = tid >> 6;
    const int lane = tid & 63;
    const int quad = lane >> 4;
    const int lo   = lane & 15;
    const int wr   = w >> 1;
    const int wc   = w & 1;
    const int m0 = blockIdx.y * 128;
    const int n0 = blockIdx.x * 128;
    const int K = EDIM;

    f32x4 acc[4][4];
#pragma unroll
    for (int i = 0; i < 4; ++i)
#pragma unroll
        for (int j = 0; j < 4; ++j) acc[i][j] = (f32x4){0.f, 0.f, 0.f, 0.f};

    const int srow = (lane >> 3);
    const int scol = (lane & 7) * 8;
    const int rotc = (lo & 7) * 8;

    for (int kt = 0; kt < K; kt += 64) {
        __syncthreads();
#pragma unroll
        for (int i = 0; i < 4; ++i) {
            const int r = w * 32 + i * 8;
            GLOAD_LDS16(A + (size_t)(m0 + r + srow) * K + kt + scol, &As[r * 64]);
            GLOAD_LDS16(W + (size_t)(n0 + r + srow) * K + kt + scol, &Bs[r * 64]);
        }
        __syncthreads();

#pragma unroll
        for (int kk = 0; kk < 2; ++kk) {
            const int cidx = (kk * 32 + quad * 8 + rotc) & 63;
            bf16x8 af[4], bf[4];
#pragma unroll
            for (int t = 0; t < 4; ++t) {
                af[t] = *(const bf16x8*)&As[(wr * 64 + t * 16 + lo) * 64 + cidx];
                bf[t] = *(const bf16x8*)&Bs[(wc * 64 + t * 16 + lo) * 64 + cidx];
            }
#pragma unroll
            for (int mt = 0; mt < 4; ++mt)
#pragma unroll
                for (int nt = 0; nt < 4; ++nt)
                    acc[mt][nt] = __builtin_amdgcn_mfma_f32_16x16x32_bf16(
                        af[mt], bf[nt], acc[mt][nt], 0, 0, 0);
        }
    }

    const int colbase = n0 + wc * 64;
#pragma unroll
    for (int mt = 0; mt < 4; ++mt) {
#pragma unroll
        for (int r = 0; r < 4; ++r) {
            const int row = m0 + wr * 64 + mt * 16 + quad * 4 + r;
            const float invr = rsqrtf(sumsq[row] * (1.0f / EDIM) + EPS);
            float* orow = outF + (size_t)row * EDIM;
#pragma unroll
            for (int nt = 0; nt < 4; ++nt)
                orow[colbase + nt * 16 + lo] = acc[mt][nt][r] * invr;
        }
    }
}

// ---------------------------------------------------------------------------
// Flash attention v6: 128-KEY iterations (half the barriers of v5).
// Ks[128][64] + Vt[64][128] staged entirely via global_load_lds (32 KB/iter,
// 64 MFMA between one barrier pair). PV runs as two wave-private half-passes
// reusing Ps[16][64] (row-rotated instead of padded -> LDS = 40 KB exactly,
// 4 blocks/CU co-resident). Causal mask on the final iteration via global
// key compare (handles both the diagonal and a half-dead 64-block).
// ---------------------------------------------------------------------------
__global__ __launch_bounds__(256) void attn_v6(const __bf16* __restrict__ qb,
                                               const __bf16* __restrict__ kb,
                                               const __bf16* __restrict__ vT,
                                               __bf16* __restrict__ attnb,
                                               float* __restrict__ sumsq) {
    __shared__ __bf16 Ks[128 * 64];      // [key][d'] rows rotated (kb layout)
    __shared__ __bf16 Vt[64 * 128];      // [d][key'] rotated per 64-block
    __shared__ __bf16 Ps[4][16][64];     // wave-private, row-rotated

    const int tid  = threadIdx.x;
    const int w    = tid >> 6;
    const int lane = tid & 63;
    const int quad = lane >> 4;
    const int lo   = lane & 15;
    const int bh   = blockIdx.x;         // 0..31
    const int y    = blockIdx.y;         // 0..31
    const int yk = y >> 3, yq = y & 7;
    const int tile = (yk == 0) ? yq : (yk == 1) ? (15 - yq)
                   : (yk == 2) ? (16 + yq) : (31 - yq);
    const int b = bh >> 4, h = bh & 15;
    const int qrow_w = tile * 64 + w * 16;

    // K staging: 128-key tile = 16 KB contiguous in kb; 4 gloads/thread.
    const __bf16* ktile0 = kb + (size_t)bh * S_LEN * 64 + tid * 8;
    // V staging: Vt[64][128] linear; thread -> (d = i*16 + tid>>4, key (tid&15)*8).
    const __bf16* vsrc = vT + ((size_t)bh * 64 + (tid >> 4)) * S_LEN + (lane & 15) * 8;
    const int ldsoff = tid * 8;

    const __bf16* qrow = qb + ((size_t)bh * S_LEN + qrow_w + lo) * 64;
    bf16x8 aq0 = *(const bf16x8*)(qrow + quad * 8);
    bf16x8 aq1 = *(const bf16x8*)(qrow + 32 + quad * 8);

    float l_acc[4] = {0.f, 0.f, 0.f, 0.f};
    f32x4 o_acc[4];
#pragma unroll
    for (int dt = 0; dt < 4; ++dt) o_acc[dt] = (f32x4){0.f, 0.f, 0.f, 0.f};

    const int njt = (tile + 2) >> 1;     // ceil((tile+1)/2) 128-key iters
    for (int jt = 0; jt < njt; ++jt) {
        __syncthreads();
#pragma unroll
        for (int i = 0; i < 4; ++i)
            GLOAD_LDS16(ktile0 + jt * 8192 + i * 2048, Ks + i * 2048 + ldsoff);
#pragma unroll
        for (int i = 0; i < 4; ++i)
            GLOAD_LDS16(vsrc + (size_t)i * 16 * S_LEN + jt * 128,
                        Vt + i * 2048 + ldsoff);
        __syncthreads();

        // --- S = Q K^T : 8 n-tiles of 16 keys ---
        f32x4 sc[8];
#pragma unroll
        for (int nt = 0; nt < 8; ++nt) {
            const int krow = nt * 16 + lo;
            const int rot  = krow & 7;
            bf16x8 k0 = *(const bf16x8*)&Ks[krow * 64 + ((quad + rot) & 7) * 8];
            bf16x8 k1 = *(const bf16x8*)&Ks[krow * 64 + ((quad + 4 + rot) & 7) * 8];
            f32x4 cc = (f32x4){0.f, 0.f, 0.f, 0.f};
            cc = __builtin_amdgcn_mfma_f32_16x16x32_bf16(aq0, k0, cc, 0, 0, 0);
            cc = __builtin_amdgcn_mfma_f32_16x16x32_bf16(aq1, k1, cc, 0, 0, 0);
            sc[nt] = cc;
        }

        // --- causal mask: final iteration only (global key compare) ---
        if (jt == njt - 1) {
#pragma unroll
            for (int nt = 0; nt < 8; ++nt)
#pragma unroll
                for (int r = 0; r < 4; ++r)
                    if (jt * 128 + nt * 16 + lo > qrow_w + quad * 4 + r)
                        sc[nt][r] = -1e30f;
        }

        // --- two half-passes: exp -> Ps (wave-private, rotated) -> PV ---
#pragma unroll
        for (int half = 0; half < 2; ++half) {
#pragma unroll
            for (int nt = 0; nt < 4; ++nt) {
#pragma unroll
                for (int r = 0; r < 4; ++r) {
                    float p = __expf(sc[half * 4 + nt][r]);
                    l_acc[r] += p;
                    const int prow = quad * 4 + r;
                    const int pcol = (nt * 16 + lo + (prow & 7) * 8) & 63;
                    Ps[w][prow][pcol] = (__bf16)p;
                }
            }
            bf16x8 ap0 = *(const bf16x8*)&Ps[w][lo][((quad + (lo & 7)) & 7) * 8];
            bf16x8 ap1 = *(const bf16x8*)&Ps[w][lo][((quad + 4 + (lo & 7)) & 7) * 8];

#pragma unroll
            for (int dt = 0; dt < 4; ++dt) {
                const int vrow = dt * 16 + lo;
                const int vrot = vrow & 7;
                bf16x8 vb0 = *(const bf16x8*)&Vt[vrow * 128 + half * 64
                                                 + ((quad + vrot) & 7) * 8];
                bf16x8 vb1 = *(const bf16x8*)&Vt[vrow * 128 + half * 64
                                                 + ((quad + 4 + vrot) & 7) * 8];
                o_acc[dt] = __builtin_amdgcn_mfma_f32_16x16x32_bf16(ap0, vb0, o_acc[dt], 0, 0, 0);
                o_acc[dt] = __builtin_amdgcn_mfma_f32_16x16x32_bf16(ap1, vb1, o_acc[dt], 0, 0, 0);
            }
        }
    }

    // --- epilogue: l-reduce, O/l -> rotated attnb + sumsq atomics ---
#pragma unroll
    for (int r = 0; r < 4; ++r) {
        float lr = l_acc[r];
        lr += __shfl_xor(lr, 1, 64);
        lr += __shfl_xor(lr, 2, 64);
        lr += __shfl_xor(lr, 4, 64);
        lr += __shfl_xor(lr, 8, 64);
        const float inv = 1.f / lr;
        const int sq = qrow_w + quad * 4 + r;
        const int token = sq * BATCH + b;
        float xv[4], ss = 0.f;
#pragma unroll
        for (int dt = 0; dt < 4; ++dt) {
            xv[dt] = o_acc[dt][r] * inv;
            ss += xv[dt] * xv[dt];
        }
        ss += __shfl_xor(ss, 1, 64);
        ss += __shfl_xor(ss, 2, 64);
        ss += __shfl_xor(ss, 4, 64);
        ss += __shfl_xor(ss, 8, 64);
        if (lo == 0) atomicAdd(&sumsq[token], ss);
        const int rot = (token & 7) * 8;
        __bf16* orow = attnb + (size_t)token * EDIM + h * 64;
#pragma unroll
        for (int dt = 0; dt < 4; ++dt)
            orow[(dt * 16 + lo + rot) & 63] = (__bf16)xv[dt];
    }
}

// ---------------------------------------------------------------------------
extern "C" void kernel_launch(void* const* d_in, const int* in_sizes, int n_in,
                              void* d_out, int out_size, void* d_ws, size_t ws_size,
                              hipStream_t stream) {
    const float* x    = (const float*)d_in[0];
    const float* cosT = (const float*)d_in[2];
    const float* sinT = (const float*)d_in[3];
    const float* Wq   = (const float*)d_in[4];
    const float* bq   = (const float*)d_in[5];
    const float* Wk   = (const float*)d_in[6];
    const float* bk   = (const float*)d_in[7];
    const float* Wv   = (const float*)d_in[8];
    const float* bv   = (const float*)d_in[9];
    const float* Wo   = (const float*)d_in[10];
    const float* nw   = (const float*)d_in[11];
    float* out = (float*)d_out;

    // Workspace (80 MiB):
    //   [ 0, 8) qb bf16 [bh][s][64]
    //   [ 8,16) attnb bf16 [token][E] (rotated GEMM-A layout)
    //   [16,17) sumsq fp32 [4096] (zeroed by cast_all)
    //   [48,56) xb bf16 (rotated)
    //   [56,64) kb bf16 [bh][s][64] rot
    //   [64,72) vT bf16 [bh][d][s] rot   (written by gemm_qkv epilogue)
    //   [72,78) Wqkvb bf16 (rotated)
    //   [78,80) Wob bf16 (rotated, nw folded)
    char* wsb = (char*)d_ws;
    const size_t MB = 1024 * 1024;
    __bf16* qb     = (__bf16*)(wsb + 0 * MB);
    __bf16* attnb  = (__bf16*)(wsb + 8 * MB);
    float*  sumsq  = (float*)(wsb + 16 * MB);
    __bf16* xb     = (__bf16*)(wsb + 48 * MB);
    __bf16* kb     = (__bf16*)(wsb + 56 * MB);
    __bf16* vT     = (__bf16*)(wsb + 64 * MB);
    __bf16* Wqkvb  = (__bf16*)(wsb + 72 * MB);
    __bf16* Wob    = (__bf16*)(wsb + 78 * MB);

    cast_all<<<(8 * 1024 * 1024) / (256 * 8), 256, 0, stream>>>(
        x, Wq, Wk, Wv, Wo, nw, xb, Wqkvb, Wob, sumsq);

    gemm_qkv<<<dim3(3072 / 128, MTOK / 256), 512, 0, stream>>>(
        xb, Wqkvb, bq, bk, bv, qb, kb, vT, cosT, sinT);

    attn_v6<<<dim3(BATCH * NH, 32), 256, 0, stream>>>(qb, kb, vT, attnb, sumsq);

    gemm_out<<<dim3(1024 / 128, MTOK / 128), 256, 0, stream>>>(
        attnb, Wob, sumsq, out);
}

// Round 12
// 226.063 us; speedup vs baseline: 1.0179x; 1.0179x over previous
//
#include <hip/hip_runtime.h>
#include <hip/hip_bf16.h>
#include <math.h>

#define S_LEN 2048
#define BATCH 2
#define EDIM 1024
#define NH 16
#define HD 64
#define MTOK (S_LEN * BATCH)   // 4096 tokens
#define SCALE 0.125f           // 64^-0.5
#define EPS 1e-6f

typedef __bf16 bf16x8 __attribute__((ext_vector_type(8)));
typedef __bf16 bf16x4 __attribute__((ext_vector_type(4)));
typedef float f32x4 __attribute__((ext_vector_type(4)));

typedef __attribute__((address_space(3))) void lds_void;
typedef const __attribute__((address_space(1))) void gbl_void;
#define GLOAD_LDS16(g, l) \
    __builtin_amdgcn_global_load_lds((gbl_void*)(g), (lds_void*)(l), 16, 0, 0)

// All bf16 GEMM operand buffers use the "row-rotation" layout: within each
// aligned 64-col block of row m, element at col c is stored at
// (c & ~63) | ((c + (m&7)*8) & 63). GEMM frag reads apply the inverse
// (rot=(lo&7)*8) -> LDS reads are 2-way (free, m136) instead of 16-way.

// ---------------------------------------------------------------------------
// cast_all (unchanged from R10)
// ---------------------------------------------------------------------------
__global__ __launch_bounds__(256) void cast_all(const float* __restrict__ x,
                                                const float* __restrict__ Wq,
                                                const float* __restrict__ Wk,
                                                const float* __restrict__ Wv,
                                                const float* __restrict__ Wo,
                                                const float* __restrict__ nw,
                                                __bf16* __restrict__ xb,
                                                __bf16* __restrict__ Wqkvb,
                                                __bf16* __restrict__ Wob,
                                                float* __restrict__ sumsq) {
    int gt = blockIdx.x * 256 + threadIdx.x;
    if (gt < 1024) ((float4*)sumsq)[gt] = (float4){0.f, 0.f, 0.f, 0.f};
    int i = gt * 8;

    const float* src;
    __bf16* dstbase;
    int row, c;
    bool isWo = false;
    if (i < (MTOK * EDIM)) {
        src = x + i;
        row = i >> 10; c = i & 1023;
        dstbase = xb + ((size_t)row << 10);
    } else {
        int j = i - MTOK * EDIM;
        int seg = j >> 20;
        int off = j & 0xFFFFF;
        src = ((seg == 0) ? Wq : (seg == 1) ? Wk : (seg == 2) ? Wv : Wo) + off;
        row = off >> 10; c = off & 1023;
        if (seg < 3) { dstbase = Wqkvb + ((size_t)(j >> 10) << 10); }
        else         { dstbase = Wob + ((size_t)row << 10); isWo = true; }
    }
    float4 a = *(const float4*)(src);
    float4 b = *(const float4*)(src + 4);
    if (isWo) {
        float4 na = *(const float4*)(nw + c);
        float4 nb = *(const float4*)(nw + c + 4);
        a.x *= na.x; a.y *= na.y; a.z *= na.z; a.w *= na.w;
        b.x *= nb.x; b.y *= nb.y; b.z *= nb.z; b.w *= nb.w;
    }
    bf16x8 o;
    o[0] = (__bf16)a.x; o[1] = (__bf16)a.y; o[2] = (__bf16)a.z; o[3] = (__bf16)a.w;
    o[4] = (__bf16)b.x; o[5] = (__bf16)b.y; o[6] = (__bf16)b.z; o[7] = (__bf16)b.w;
    int rot = (row & 7) * 8;
    int cp = (c & ~63) | ((c + rot) & 63);
    *(bf16x8*)(dstbase + cp) = o;
}

// ---------------------------------------------------------------------------
// QKV GEMM v2: 128x128 tile, 256 threads = 4 waves (2Mx2N) -> 768 blocks =
// 3.0 blocks/CU, NO dispatch tail (R10's 256x128 had 384 blocks = 1.5/CU:
// half the CUs idle for the second round). Same zero-conflict swizzled body
// as gemm_out (R7 measured this shape at 58us WITH 9.4e6 conflict-cycles;
// conflicts are now 0 -> ~46us expected). Fused epilogues as R10: seg0/1 ->
// RoPE -> qb/kb; seg2 -> chunked wave-private transpose -> vT.
// ---------------------------------------------------------------------------
__global__ __launch_bounds__(256) void gemm_qkv(const __bf16* __restrict__ A,
                                                const __bf16* __restrict__ W,
                                                const float* __restrict__ bias0,
                                                const float* __restrict__ bias1,
                                                const float* __restrict__ bias2,
                                                __bf16* __restrict__ qb,
                                                __bf16* __restrict__ kb,
                                                __bf16* __restrict__ vT,
                                                const float* __restrict__ cosT,
                                                const float* __restrict__ sinT) {
    __shared__ __bf16 SMEM[128 * 64 + 128 * 64];   // As | Bs, 32 KB
    __bf16* As = SMEM;
    __bf16* Bs = SMEM + 128 * 64;

    const int tid  = threadIdx.x;
    const int w    = tid >> 6;       // 0..3
    const int lane = tid & 63;
    const int quad = lane >> 4;
    const int lo   = lane & 15;
    const int wr   = w >> 1;         // M-wave 0..1
    const int wc   = w & 1;          // N-wave 0..1
    const int m0 = blockIdx.y * 128;
    const int n0 = blockIdx.x * 128;
    const int K = EDIM;

    f32x4 acc[4][4];
#pragma unroll
    for (int i = 0; i < 4; ++i)
#pragma unroll
        for (int j = 0; j < 4; ++j) acc[i][j] = (f32x4){0.f, 0.f, 0.f, 0.f};

    const int srow = (lane >> 3);        // 0..7
    const int scol = (lane & 7) * 8;
    const int rotc = (lo & 7) * 8;       // inverse of the row-rotation

    for (int kt = 0; kt < K; kt += 64) {
        __syncthreads();
#pragma unroll
        for (int i = 0; i < 4; ++i) {
            const int r = w * 32 + i * 8;
            GLOAD_LDS16(A + (size_t)(m0 + r + srow) * K + kt + scol, &As[r * 64]);
            GLOAD_LDS16(W + (size_t)(n0 + r + srow) * K + kt + scol, &Bs[r * 64]);
        }
        __syncthreads();

#pragma unroll
        for (int kk = 0; kk < 2; ++kk) {
            const int cidx = (kk * 32 + quad * 8 + rotc) & 63;
            bf16x8 af[4], bf[4];
#pragma unroll
            for (int t = 0; t < 4; ++t) {
                af[t] = *(const bf16x8*)&As[(wr * 64 + t * 16 + lo) * 64 + cidx];
                bf[t] = *(const bf16x8*)&Bs[(wc * 64 + t * 16 + lo) * 64 + cidx];
            }
#pragma unroll
            for (int mt = 0; mt < 4; ++mt)
#pragma unroll
                for (int nt = 0; nt < 4; ++nt)
                    acc[mt][nt] = __builtin_amdgcn_mfma_f32_16x16x32_bf16(
                        af[mt], bf[nt], acc[mt][nt], 0, 0, 0);
        }
    }

    const int seg = n0 >> 10;
    const int colbase = (n0 & 1023) + wc * 64;

    if (seg < 2) {
        // --- fused RoPE epilogue: wave covers one head (64 cols) ---
        const float* bp = (seg == 0) ? bias0 : bias1;
        __bf16* dstb = (seg == 0) ? qb : kb;
        const int h = colbase >> 6;
        float b0v = bp[colbase + lo];
        float b1v = bp[colbase + 16 + lo];
        float b2v = bp[colbase + 32 + lo];
        float b3v = bp[colbase + 48 + lo];
#pragma unroll
        for (int mt = 0; mt < 4; ++mt) {
#pragma unroll
            for (int r = 0; r < 4; ++r) {
                const int m = m0 + wr * 64 + mt * 16 + quad * 4 + r;
                const int s = m >> 1, bidx = m & 1;
                float x0 = acc[mt][0][r] + b0v;
                float x1 = acc[mt][1][r] + b1v;
                float x2 = acc[mt][2][r] + b2v;
                float x3 = acc[mt][3][r] + b3v;
                const float* ct = cosT + s * 64;
                const float* st = sinT + s * 64;
                float o0 = x0 * ct[lo]      - x2 * st[lo];
                float o1 = x1 * ct[16 + lo] - x3 * st[16 + lo];
                float o2 = x2 * ct[32 + lo] + x0 * st[32 + lo];
                float o3 = x3 * ct[48 + lo] + x1 * st[48 + lo];
                __bf16* row = dstb + ((size_t)(bidx * NH + h) * S_LEN + s) * 64;
                if (seg == 0) {
                    row[lo]      = (__bf16)(o0 * SCALE);
                    row[16 + lo] = (__bf16)(o1 * SCALE);
                    row[32 + lo] = (__bf16)(o2 * SCALE);
                    row[48 + lo] = (__bf16)(o3 * SCALE);
                } else {
                    const int rot = (s & 7) * 8;
                    row[(lo + rot) & 63]      = (__bf16)o0;
                    row[(16 + lo + rot) & 63] = (__bf16)o1;
                    row[(32 + lo + rot) & 63] = (__bf16)o2;
                    row[(48 + lo + rot) & 63] = (__bf16)o3;
                }
            }
        }
    } else {
        // --- v segment: chunked wave-private 64x64 transpose -> vT ---
        // 4 chunks of 16 d-cols; per chunk each wave uses a private 16x68
        // region (2.2 KB; 4 waves = 8.7 KB inside SMEM) -> all waves
        // concurrent, no barrier between write and readback.
        __syncthreads();   // all waves done frag-reading As/Bs
        const int h = ((n0 - 2048) >> 6) + wc;
        const int sbase = (m0 >> 1) + wr * 32;
        float bv4[4];
        bv4[0] = bias2[h * 64 + lo];
        bv4[1] = bias2[h * 64 + 16 + lo];
        bv4[2] = bias2[h * 64 + 32 + lo];
        bv4[3] = bias2[h * 64 + 48 + lo];
        __bf16* Treg = SMEM + w * 1088;      // 16 rows x 68
        const int rdrow = lane >> 2;          // 0..15
        const int rdcol = (lane & 3) * 16;    // 0,16,32,48
#pragma unroll
        for (int nt = 0; nt < 4; ++nt) {
#pragma unroll
            for (int mt = 0; mt < 4; ++mt)
#pragma unroll
                for (int r = 0; r < 4; ++r) {
                    const int tl = mt * 16 + quad * 4 + r;
                    const int li = (tl & 1) * 32 + (tl >> 1);
                    Treg[lo * 68 + li] = (__bf16)(acc[mt][nt][r] + bv4[nt]);
                }
            const int d = nt * 16 + rdrow;
            const int rot = (d & 7) * 8;
            const int bidx = rdcol >> 5;
            const int soff = rdcol & 31;
            bf16x8 v0 = *(const bf16x8*)&Treg[rdrow * 68 + rdcol];
            bf16x8 v1 = *(const bf16x8*)&Treg[rdrow * 68 + rdcol + 8];
            __bf16* base = vT + ((size_t)((bidx * NH + h) * 64 + d)) * S_LEN;
            const int s0 = sbase + soff;
            const int s1 = s0 + 8;
            *(bf16x8*)(base + (s0 & ~63) + (((s0 & 63) + rot) & 63)) = v0;
            *(bf16x8*)(base + (s1 & ~63) + (((s1 & 63) + rot) & 63)) = v1;
        }
    }
}

// ---------------------------------------------------------------------------
// Out-proj GEMM (unchanged from R10): folded-RMSNorm epilogue.
// ---------------------------------------------------------------------------
__global__ __launch_bounds__(256) void gemm_out(const __bf16* __restrict__ A,
                                                const __bf16* __restrict__ W,
                                                const float* __restrict__ sumsq,
                                                float* __restrict__ outF) {
    __shared__ __bf16 As[128 * 64];
    __shared__ __bf16 Bs[128 * 64];

    const int tid  = threadIdx.x;
    const int w    = tid >> 6;
    const int lane = tid & 63;
    const int quad = lane >> 4;
    const int lo   = lane & 15;
    const int wr   = w >> 1;
    const int wc   = w & 1;
    const int m0 = blockIdx.y * 128;
    const int n0 = blockIdx.x * 128;
    const int K = EDIM;

    f32x4 acc[4][4];
#pragma unroll
    for (int i = 0; i < 4; ++i)
#pragma unroll
        for (int j = 0; j < 4; ++j) acc[i][j] = (f32x4){0.f, 0.f, 0.f, 0.f};

    const int srow = (lane >> 3);
    const int scol = (lane & 7) * 8;
    const int rotc = (lo & 7) * 8;

    for (int kt = 0; kt < K; kt += 64) {
        __syncthreads();
#pragma unroll
        for (int i = 0; i < 4; ++i) {
            const int r = w * 32 + i * 8;
            GLOAD_LDS16(A + (size_t)(m0 + r + srow) * K + kt + scol, &As[r * 64]);
            GLOAD_LDS16(W + (size_t)(n0 + r + srow) * K + kt + scol, &Bs[r * 64]);
        }
        __syncthreads();

#pragma unroll
        for (int kk = 0; kk < 2; ++kk) {
            const int cidx = (kk * 32 + quad * 8 + rotc) & 63;
            bf16x8 af[4], bf[4];
#pragma unroll
            for (int t = 0; t < 4; ++t) {
                af[t] = *(const bf16x8*)&As[(wr * 64 + t * 16 + lo) * 64 + cidx];
                bf[t] = *(const bf16x8*)&Bs[(wc * 64 + t * 16 + lo) * 64 + cidx];
            }
#pragma unroll
            for (int mt = 0; mt < 4; ++mt)
#pragma unroll
                for (int nt = 0; nt < 4; ++nt)
                    acc[mt][nt] = __builtin_amdgcn_mfma_f32_16x16x32_bf16(
                        af[mt], bf[nt], acc[mt][nt], 0, 0, 0);
        }
    }

    const int colbase = n0 + wc * 64;
#pragma unroll
    for (int mt = 0; mt < 4; ++mt) {
#pragma unroll
        for (int r = 0; r < 4; ++r) {
            const int row = m0 + wr * 64 + mt * 16 + quad * 4 + r;
            const float invr = rsqrtf(sumsq[row] * (1.0f / EDIM) + EPS);
            float* orow = outF + (size_t)row * EDIM;
#pragma unroll
            for (int nt = 0; nt < 4; ++nt)
                orow[colbase + nt * 16 + lo] = acc[mt][nt][r] * invr;
        }
    }
}

// ---------------------------------------------------------------------------
// Flash attention v6 (unchanged from R11): 128-key iterations.
// ---------------------------------------------------------------------------
__global__ __launch_bounds__(256) void attn_v6(const __bf16* __restrict__ qb,
                                               const __bf16* __restrict__ kb,
                                               const __bf16* __restrict__ vT,
                                               __bf16* __restrict__ attnb,
                                               float* __restrict__ sumsq) {
    __shared__ __bf16 Ks[128 * 64];      // [key][d'] rows rotated (kb layout)
    __shared__ __bf16 Vt[64 * 128];      // [d][key'] rotated per 64-block
    __shared__ __bf16 Ps[4][16][64];     // wave-private, row-rotated

    const int tid  = threadIdx.x;
    const int w    = tid >> 6;
    const int lane = tid & 63;
    const int quad = lane >> 4;
    const int lo   = lane & 15;
    const int bh   = blockIdx.x;         // 0..31
    const int y    = blockIdx.y;         // 0..31
    const int yk = y >> 3, yq = y & 7;
    const int tile = (yk == 0) ? yq : (yk == 1) ? (15 - yq)
                   : (yk == 2) ? (16 + yq) : (31 - yq);
    const int b = bh >> 4, h = bh & 15;
    const int qrow_w = tile * 64 + w * 16;

    const __bf16* ktile0 = kb + (size_t)bh * S_LEN * 64 + tid * 8;
    const __bf16* vsrc = vT + ((size_t)bh * 64 + (tid >> 4)) * S_LEN + (lane & 15) * 8;
    const int ldsoff = tid * 8;

    const __bf16* qrow = qb + ((size_t)bh * S_LEN + qrow_w + lo) * 64;
    bf16x8 aq0 = *(const bf16x8*)(qrow + quad * 8);
    bf16x8 aq1 = *(const bf16x8*)(qrow + 32 + quad * 8);

    float l_acc[4] = {0.f, 0.f, 0.f, 0.f};
    f32x4 o_acc[4];
#pragma unroll
    for (int dt = 0; dt < 4; ++dt) o_acc[dt] = (f32x4){0.f, 0.f, 0.f, 0.f};

    const int njt = (tile + 2) >> 1;
    for (int jt = 0; jt < njt; ++jt) {
        __syncthreads();
#pragma unroll
        for (int i = 0; i < 4; ++i)
            GLOAD_LDS16(ktile0 + jt * 8192 + i * 2048, Ks + i * 2048 + ldsoff);
#pragma unroll
        for (int i = 0; i < 4; ++i)
            GLOAD_LDS16(vsrc + (size_t)i * 16 * S_LEN + jt * 128,
                        Vt + i * 2048 + ldsoff);
        __syncthreads();

        f32x4 sc[8];
#pragma unroll
        for (int nt = 0; nt < 8; ++nt) {
            const int krow = nt * 16 + lo;
            const int rot  = krow & 7;
            bf16x8 k0 = *(const bf16x8*)&Ks[krow * 64 + ((quad + rot) & 7) * 8];
            bf16x8 k1 = *(const bf16x8*)&Ks[krow * 64 + ((quad + 4 + rot) & 7) * 8];
            f32x4 cc = (f32x4){0.f, 0.f, 0.f, 0.f};
            cc = __builtin_amdgcn_mfma_f32_16x16x32_bf16(aq0, k0, cc, 0, 0, 0);
            cc = __builtin_amdgcn_mfma_f32_16x16x32_bf16(aq1, k1, cc, 0, 0, 0);
            sc[nt] = cc;
        }

        if (jt == njt - 1) {
#pragma unroll
            for (int nt = 0; nt < 8; ++nt)
#pragma unroll
                for (int r = 0; r < 4; ++r)
                    if (jt * 128 + nt * 16 + lo > qrow_w + quad * 4 + r)
                        sc[nt][r] = -1e30f;
        }

#pragma unroll
        for (int half = 0; half < 2; ++half) {
#pragma unroll
            for (int nt = 0; nt < 4; ++nt) {
#pragma unroll
                for (int r = 0; r < 4; ++r) {
                    float p = __expf(sc[half * 4 + nt][r]);
                    l_acc[r] += p;
                    const int prow = quad * 4 + r;
                    const int pcol = (nt * 16 + lo + (prow & 7) * 8) & 63;
                    Ps[w][prow][pcol] = (__bf16)p;
                }
            }
            bf16x8 ap0 = *(const bf16x8*)&Ps[w][lo][((quad + (lo & 7)) & 7) * 8];
            bf16x8 ap1 = *(const bf16x8*)&Ps[w][lo][((quad + 4 + (lo & 7)) & 7) * 8];

#pragma unroll
            for (int dt = 0; dt < 4; ++dt) {
                const int vrow = dt * 16 + lo;
                const int vrot = vrow & 7;
                bf16x8 vb0 = *(const bf16x8*)&Vt[vrow * 128 + half * 64
                                                 + ((quad + vrot) & 7) * 8];
                bf16x8 vb1 = *(const bf16x8*)&Vt[vrow * 128 + half * 64
                                                 + ((quad + 4 + vrot) & 7) * 8];
                o_acc[dt] = __builtin_amdgcn_mfma_f32_16x16x32_bf16(ap0, vb0, o_acc[dt], 0, 0, 0);
                o_acc[dt] = __builtin_amdgcn_mfma_f32_16x16x32_bf16(ap1, vb1, o_acc[dt], 0, 0, 0);
            }
        }
    }

#pragma unroll
    for (int r = 0; r < 4; ++r) {
        float lr = l_acc[r];
        lr += __shfl_xor(lr, 1, 64);
        lr += __shfl_xor(lr, 2, 64);
        lr += __shfl_xor(lr, 4, 64);
        lr += __shfl_xor(lr, 8, 64);
        const float inv = 1.f / lr;
        const int sq = qrow_w + quad * 4 + r;
        const int token = sq * BATCH + b;
        float xv[4], ss = 0.f;
#pragma unroll
        for (int dt = 0; dt < 4; ++dt) {
            xv[dt] = o_acc[dt][r] * inv;
            ss += xv[dt] * xv[dt];
        }
        ss += __shfl_xor(ss, 1, 64);
        ss += __shfl_xor(ss, 2, 64);
        ss += __shfl_xor(ss, 4, 64);
        ss += __shfl_xor(ss, 8, 64);
        if (lo == 0) atomicAdd(&sumsq[token], ss);
        const int rot = (token & 7) * 8;
        __bf16* orow = attnb + (size_t)token * EDIM + h * 64;
#pragma unroll
        for (int dt = 0; dt < 4; ++dt)
            orow[(dt * 16 + lo + rot) & 63] = (__bf16)xv[dt];
    }
}

// ---------------------------------------------------------------------------
extern "C" void kernel_launch(void* const* d_in, const int* in_sizes, int n_in,
                              void* d_out, int out_size, void* d_ws, size_t ws_size,
                              hipStream_t stream) {
    const float* x    = (const float*)d_in[0];
    const float* cosT = (const float*)d_in[2];
    const float* sinT = (const float*)d_in[3];
    const float* Wq   = (const float*)d_in[4];
    const float* bq   = (const float*)d_in[5];
    const float* Wk   = (const float*)d_in[6];
    const float* bk   = (const float*)d_in[7];
    const float* Wv   = (const float*)d_in[8];
    const float* bv   = (const float*)d_in[9];
    const float* Wo   = (const float*)d_in[10];
    const float* nw   = (const float*)d_in[11];
    float* out = (float*)d_out;

    // Workspace (80 MiB):
    //   [ 0, 8) qb bf16 [bh][s][64]
    //   [ 8,16) attnb bf16 [token][E] (rotated GEMM-A layout)
    //   [16,17) sumsq fp32 [4096] (zeroed by cast_all)
    //   [48,56) xb bf16 (rotated)
    //   [56,64) kb bf16 [bh][s][64] rot
    //   [64,72) vT bf16 [bh][d][s] rot   (written by gemm_qkv epilogue)
    //   [72,78) Wqkvb bf16 (rotated)
    //   [78,80) Wob bf16 (rotated, nw folded)
    char* wsb = (char*)d_ws;
    const size_t MB = 1024 * 1024;
    __bf16* qb     = (__bf16*)(wsb + 0 * MB);
    __bf16* attnb  = (__bf16*)(wsb + 8 * MB);
    float*  sumsq  = (float*)(wsb + 16 * MB);
    __bf16* xb     = (__bf16*)(wsb + 48 * MB);
    __bf16* kb     = (__bf16*)(wsb + 56 * MB);
    __bf16* vT     = (__bf16*)(wsb + 64 * MB);
    __bf16* Wqkvb  = (__bf16*)(wsb + 72 * MB);
    __bf16* Wob    = (__bf16*)(wsb + 78 * MB);

    cast_all<<<(8 * 1024 * 1024) / (256 * 8), 256, 0, stream>>>(
        x, Wq, Wk, Wv, Wo, nw, xb, Wqkvb, Wob, sumsq);

    // 128x128 tiles -> 768 blocks = 3.0/CU, no tail
    gemm_qkv<<<dim3(3072 / 128, MTOK / 128), 256, 0, stream>>>(
        xb, Wqkvb, bq, bk, bv, qb, kb, vT, cosT, sinT);

    attn_v6<<<dim3(BATCH * NH, 32), 256, 0, stream>>>(qb, kb, vT, attnb, sumsq);

    gemm_out<<<dim3(1024 / 128, MTOK / 128), 256, 0, stream>>>(
        attnb, Wob, sumsq, out);
}

// Round 13
// 218.621 us; speedup vs baseline: 1.0526x; 1.0340x over previous
//
#include <hip/hip_runtime.h>
#include <hip/hip_bf16.h>
#include <math.h>

#define S_LEN 2048
#define BATCH 2
#define EDIM 1024
#define NH 16
#define HD 64
#define MTOK (S_LEN * BATCH)   // 4096 tokens
#define SCALE 0.125f           // 64^-0.5
#define EPS 1e-6f

typedef __bf16 bf16x8 __attribute__((ext_vector_type(8)));
typedef __bf16 bf16x4 __attribute__((ext_vector_type(4)));
typedef float f32x4 __attribute__((ext_vector_type(4)));

typedef __attribute__((address_space(3))) void lds_void;
typedef const __attribute__((address_space(1))) void gbl_void;
#define GLOAD_LDS16(g, l) \
    __builtin_amdgcn_global_load_lds((gbl_void*)(g), (lds_void*)(l), 16, 0, 0)

// All bf16 GEMM operand buffers use the "row-rotation" layout: within each
// aligned 64-col block of row m, element at col c is stored at
// (c & ~63) | ((c + (m&7)*8) & 63). GEMM frag reads apply the inverse
// (rot=(lo&7)*8) -> LDS reads are 2-way (free, m136) instead of 16-way.

// ---------------------------------------------------------------------------
// cast_all (unchanged from R10)
// ---------------------------------------------------------------------------
__global__ __launch_bounds__(256) void cast_all(const float* __restrict__ x,
                                                const float* __restrict__ Wq,
                                                const float* __restrict__ Wk,
                                                const float* __restrict__ Wv,
                                                const float* __restrict__ Wo,
                                                const float* __restrict__ nw,
                                                __bf16* __restrict__ xb,
                                                __bf16* __restrict__ Wqkvb,
                                                __bf16* __restrict__ Wob,
                                                float* __restrict__ sumsq) {
    int gt = blockIdx.x * 256 + threadIdx.x;
    if (gt < 1024) ((float4*)sumsq)[gt] = (float4){0.f, 0.f, 0.f, 0.f};
    int i = gt * 8;

    const float* src;
    __bf16* dstbase;
    int row, c;
    bool isWo = false;
    if (i < (MTOK * EDIM)) {
        src = x + i;
        row = i >> 10; c = i & 1023;
        dstbase = xb + ((size_t)row << 10);
    } else {
        int j = i - MTOK * EDIM;
        int seg = j >> 20;
        int off = j & 0xFFFFF;
        src = ((seg == 0) ? Wq : (seg == 1) ? Wk : (seg == 2) ? Wv : Wo) + off;
        row = off >> 10; c = off & 1023;
        if (seg < 3) { dstbase = Wqkvb + ((size_t)(j >> 10) << 10); }
        else         { dstbase = Wob + ((size_t)row << 10); isWo = true; }
    }
    float4 a = *(const float4*)(src);
    float4 b = *(const float4*)(src + 4);
    if (isWo) {
        float4 na = *(const float4*)(nw + c);
        float4 nb = *(const float4*)(nw + c + 4);
        a.x *= na.x; a.y *= na.y; a.z *= na.z; a.w *= na.w;
        b.x *= nb.x; b.y *= nb.y; b.z *= nb.z; b.w *= nb.w;
    }
    bf16x8 o;
    o[0] = (__bf16)a.x; o[1] = (__bf16)a.y; o[2] = (__bf16)a.z; o[3] = (__bf16)a.w;
    o[4] = (__bf16)b.x; o[5] = (__bf16)b.y; o[6] = (__bf16)b.z; o[7] = (__bf16)b.w;
    int rot = (row & 7) * 8;
    int cp = (c & ~63) | ((c + rot) & 63);
    *(bf16x8*)(dstbase + cp) = o;
}

// ---------------------------------------------------------------------------
// QKV GEMM (unchanged from R12): 128x128, 768 blocks = 3/CU, fused RoPE +
// chunked wave-private V transpose epilogues.
// ---------------------------------------------------------------------------
__global__ __launch_bounds__(256) void gemm_qkv(const __bf16* __restrict__ A,
                                                const __bf16* __restrict__ W,
                                                const float* __restrict__ bias0,
                                                const float* __restrict__ bias1,
                                                const float* __restrict__ bias2,
                                                __bf16* __restrict__ qb,
                                                __bf16* __restrict__ kb,
                                                __bf16* __restrict__ vT,
                                                const float* __restrict__ cosT,
                                                const float* __restrict__ sinT) {
    __shared__ __bf16 SMEM[128 * 64 + 128 * 64];   // As | Bs, 32 KB
    __bf16* As = SMEM;
    __bf16* Bs = SMEM + 128 * 64;

    const int tid  = threadIdx.x;
    const int w    = tid >> 6;       // 0..3
    const int lane = tid & 63;
    const int quad = lane >> 4;
    const int lo   = lane & 15;
    const int wr   = w >> 1;         // M-wave 0..1
    const int wc   = w & 1;          // N-wave 0..1
    const int m0 = blockIdx.y * 128;
    const int n0 = blockIdx.x * 128;
    const int K = EDIM;

    f32x4 acc[4][4];
#pragma unroll
    for (int i = 0; i < 4; ++i)
#pragma unroll
        for (int j = 0; j < 4; ++j) acc[i][j] = (f32x4){0.f, 0.f, 0.f, 0.f};

    const int srow = (lane >> 3);        // 0..7
    const int scol = (lane & 7) * 8;
    const int rotc = (lo & 7) * 8;       // inverse of the row-rotation

    for (int kt = 0; kt < K; kt += 64) {
        __syncthreads();
#pragma unroll
        for (int i = 0; i < 4; ++i) {
            const int r = w * 32 + i * 8;
            GLOAD_LDS16(A + (size_t)(m0 + r + srow) * K + kt + scol, &As[r * 64]);
            GLOAD_LDS16(W + (size_t)(n0 + r + srow) * K + kt + scol, &Bs[r * 64]);
        }
        __syncthreads();

#pragma unroll
        for (int kk = 0; kk < 2; ++kk) {
            const int cidx = (kk * 32 + quad * 8 + rotc) & 63;
            bf16x8 af[4], bf[4];
#pragma unroll
            for (int t = 0; t < 4; ++t) {
                af[t] = *(const bf16x8*)&As[(wr * 64 + t * 16 + lo) * 64 + cidx];
                bf[t] = *(const bf16x8*)&Bs[(wc * 64 + t * 16 + lo) * 64 + cidx];
            }
#pragma unroll
            for (int mt = 0; mt < 4; ++mt)
#pragma unroll
                for (int nt = 0; nt < 4; ++nt)
                    acc[mt][nt] = __builtin_amdgcn_mfma_f32_16x16x32_bf16(
                        af[mt], bf[nt], acc[mt][nt], 0, 0, 0);
        }
    }

    const int seg = n0 >> 10;
    const int colbase = (n0 & 1023) + wc * 64;

    if (seg < 2) {
        // --- fused RoPE epilogue: wave covers one head (64 cols) ---
        const float* bp = (seg == 0) ? bias0 : bias1;
        __bf16* dstb = (seg == 0) ? qb : kb;
        const int h = colbase >> 6;
        float b0v = bp[colbase + lo];
        float b1v = bp[colbase + 16 + lo];
        float b2v = bp[colbase + 32 + lo];
        float b3v = bp[colbase + 48 + lo];
#pragma unroll
        for (int mt = 0; mt < 4; ++mt) {
#pragma unroll
            for (int r = 0; r < 4; ++r) {
                const int m = m0 + wr * 64 + mt * 16 + quad * 4 + r;
                const int s = m >> 1, bidx = m & 1;
                float x0 = acc[mt][0][r] + b0v;
                float x1 = acc[mt][1][r] + b1v;
                float x2 = acc[mt][2][r] + b2v;
                float x3 = acc[mt][3][r] + b3v;
                const float* ct = cosT + s * 64;
                const float* st = sinT + s * 64;
                float o0 = x0 * ct[lo]      - x2 * st[lo];
                float o1 = x1 * ct[16 + lo] - x3 * st[16 + lo];
                float o2 = x2 * ct[32 + lo] + x0 * st[32 + lo];
                float o3 = x3 * ct[48 + lo] + x1 * st[48 + lo];
                __bf16* row = dstb + ((size_t)(bidx * NH + h) * S_LEN + s) * 64;
                if (seg == 0) {
                    row[lo]      = (__bf16)(o0 * SCALE);
                    row[16 + lo] = (__bf16)(o1 * SCALE);
                    row[32 + lo] = (__bf16)(o2 * SCALE);
                    row[48 + lo] = (__bf16)(o3 * SCALE);
                } else {
                    const int rot = (s & 7) * 8;
                    row[(lo + rot) & 63]      = (__bf16)o0;
                    row[(16 + lo + rot) & 63] = (__bf16)o1;
                    row[(32 + lo + rot) & 63] = (__bf16)o2;
                    row[(48 + lo + rot) & 63] = (__bf16)o3;
                }
            }
        }
    } else {
        // --- v segment: chunked wave-private 64x64 transpose -> vT ---
        __syncthreads();   // all waves done frag-reading As/Bs
        const int h = ((n0 - 2048) >> 6) + wc;
        const int sbase = (m0 >> 1) + wr * 32;
        float bv4[4];
        bv4[0] = bias2[h * 64 + lo];
        bv4[1] = bias2[h * 64 + 16 + lo];
        bv4[2] = bias2[h * 64 + 32 + lo];
        bv4[3] = bias2[h * 64 + 48 + lo];
        __bf16* Treg = SMEM + w * 1088;      // 16 rows x 68
        const int rdrow = lane >> 2;          // 0..15
        const int rdcol = (lane & 3) * 16;    // 0,16,32,48
#pragma unroll
        for (int nt = 0; nt < 4; ++nt) {
#pragma unroll
            for (int mt = 0; mt < 4; ++mt)
#pragma unroll
                for (int r = 0; r < 4; ++r) {
                    const int tl = mt * 16 + quad * 4 + r;
                    const int li = (tl & 1) * 32 + (tl >> 1);
                    Treg[lo * 68 + li] = (__bf16)(acc[mt][nt][r] + bv4[nt]);
                }
            const int d = nt * 16 + rdrow;
            const int rot = (d & 7) * 8;
            const int bidx = rdcol >> 5;
            const int soff = rdcol & 31;
            bf16x8 v0 = *(const bf16x8*)&Treg[rdrow * 68 + rdcol];
            bf16x8 v1 = *(const bf16x8*)&Treg[rdrow * 68 + rdcol + 8];
            __bf16* base = vT + ((size_t)((bidx * NH + h) * 64 + d)) * S_LEN;
            const int s0 = sbase + soff;
            const int s1 = s0 + 8;
            *(bf16x8*)(base + (s0 & ~63) + (((s0 & 63) + rot) & 63)) = v0;
            *(bf16x8*)(base + (s1 & ~63) + (((s1 & 63) + rot) & 63)) = v1;
        }
    }
}

// ---------------------------------------------------------------------------
// Out-proj GEMM (unchanged): folded-RMSNorm epilogue.
// ---------------------------------------------------------------------------
__global__ __launch_bounds__(256) void gemm_out(const __bf16* __restrict__ A,
                                                const __bf16* __restrict__ W,
                                                const float* __restrict__ sumsq,
                                                float* __restrict__ outF) {
    __shared__ __bf16 As[128 * 64];
    __shared__ __bf16 Bs[128 * 64];

    const int tid  = threadIdx.x;
    const int w    = tid >> 6;
    const int lane = tid & 63;
    const int quad = lane >> 4;
    const int lo   = lane & 15;
    const int wr   = w >> 1;
    const int wc   = w & 1;
    const int m0 = blockIdx.y * 128;
    const int n0 = blockIdx.x * 128;
    const int K = EDIM;

    f32x4 acc[4][4];
#pragma unroll
    for (int i = 0; i < 4; ++i)
#pragma unroll
        for (int j = 0; j < 4; ++j) acc[i][j] = (f32x4){0.f, 0.f, 0.f, 0.f};

    const int srow = (lane >> 3);
    const int scol = (lane & 7) * 8;
    const int rotc = (lo & 7) * 8;

    for (int kt = 0; kt < K; kt += 64) {
        __syncthreads();
#pragma unroll
        for (int i = 0; i < 4; ++i) {
            const int r = w * 32 + i * 8;
            GLOAD_LDS16(A + (size_t)(m0 + r + srow) * K + kt + scol, &As[r * 64]);
            GLOAD_LDS16(W + (size_t)(n0 + r + srow) * K + kt + scol, &Bs[r * 64]);
        }
        __syncthreads();

#pragma unroll
        for (int kk = 0; kk < 2; ++kk) {
            const int cidx = (kk * 32 + quad * 8 + rotc) & 63;
            bf16x8 af[4], bf[4];
#pragma unroll
            for (int t = 0; t < 4; ++t) {
                af[t] = *(const bf16x8*)&As[(wr * 64 + t * 16 + lo) * 64 + cidx];
                bf[t] = *(const bf16x8*)&Bs[(wc * 64 + t * 16 + lo) * 64 + cidx];
            }
#pragma unroll
            for (int mt = 0; mt < 4; ++mt)
#pragma unroll
                for (int nt = 0; nt < 4; ++nt)
                    acc[mt][nt] = __builtin_amdgcn_mfma_f32_16x16x32_bf16(
                        af[mt], bf[nt], acc[mt][nt], 0, 0, 0);
        }
    }

    const int colbase = n0 + wc * 64;
#pragma unroll
    for (int mt = 0; mt < 4; ++mt) {
#pragma unroll
        for (int r = 0; r < 4; ++r) {
            const int row = m0 + wr * 64 + mt * 16 + quad * 4 + r;
            const float invr = rsqrtf(sumsq[row] * (1.0f / EDIM) + EPS);
            float* orow = outF + (size_t)row * EDIM;
#pragma unroll
            for (int nt = 0; nt < 4; ++nt)
                orow[colbase + nt * 16 + lo] = acc[mt][nt][r] * invr;
        }
    }
}

// ---------------------------------------------------------------------------
// Flash attention v7: UNIFORM-DURATION blocks via pair {p,31-p} + key-parity
// split. Block (bh, z): p=z>>1, hf=z&1 processes qtiles p and 31-p over key
// tiles kt ≡ hf (mod 2) -> every block runs 16-17 64-key iterations (v6's
// {1..16}-iter mix left each CU waiting on its longest block: 52% packing).
// No max-subtraction, so softmax partials combine LINEARLY in a separate
// combine kernel. Body = v5 staging (Ks/Vt via global_load_lds, Ps padded
// [16][72] -> v5-level conflicts). Epilogue stores raw partial O (bf16) + l.
// ---------------------------------------------------------------------------
__global__ __launch_bounds__(256) void attn_v7(const __bf16* __restrict__ qb,
                                               const __bf16* __restrict__ kb,
                                               const __bf16* __restrict__ vT,
                                               __bf16* __restrict__ Opart,
                                               float* __restrict__ lpart) {
    __shared__ __bf16 Ks[64 * 64];       // [key][d'] rows rotated (kb layout)
    __shared__ __bf16 Vt[64 * 64];       // [d][key'] rotated (vT layout)
    __shared__ __bf16 Ps[4][16][72];     // wave-private, padded

    const int tid  = threadIdx.x;
    const int w    = tid >> 6;
    const int lane = tid & 63;
    const int quad = lane >> 4;
    const int lo   = lane & 15;
    const int bh   = blockIdx.x;         // 0..31
    const int z    = blockIdx.y;         // 0..31
    const int p    = z >> 1;             // pair 0..15
    const int hf   = z & 1;              // key-parity half

    const __bf16* ktile0 = kb + (size_t)bh * S_LEN * 64 + tid * 8;
    const int vd0 = w * 16 + (lane >> 3);
    const __bf16* vsrc0 = vT + ((size_t)bh * 64 + vd0) * S_LEN + (lane & 7) * 8;
    const __bf16* vsrc1 = vsrc0 + 8 * S_LEN;

#pragma unroll
    for (int ti = 0; ti < 2; ++ti) {
        const int tile = ti ? (31 - p) : p;
        const int qrow_w = tile * 64 + w * 16;

        const __bf16* qrow = qb + ((size_t)bh * S_LEN + qrow_w + lo) * 64;
        bf16x8 aq0 = *(const bf16x8*)(qrow + quad * 8);
        bf16x8 aq1 = *(const bf16x8*)(qrow + 32 + quad * 8);

        float l_acc[4] = {0.f, 0.f, 0.f, 0.f};
        f32x4 o_acc[4];
#pragma unroll
        for (int dt = 0; dt < 4; ++dt) o_acc[dt] = (f32x4){0.f, 0.f, 0.f, 0.f};

        for (int kt = hf; kt <= tile; kt += 2) {
            __syncthreads();
            GLOAD_LDS16(ktile0 + kt * 4096,        Ks + tid * 8);
            GLOAD_LDS16(ktile0 + kt * 4096 + 2048, Ks + 2048 + tid * 8);
            GLOAD_LDS16(vsrc0 + kt * 64, Vt + vd0 * 64 + (lane & 7) * 8);
            GLOAD_LDS16(vsrc1 + kt * 64, Vt + (vd0 + 8) * 64 + (lane & 7) * 8);
            __syncthreads();

            f32x4 sc[4];
#pragma unroll
            for (int nt = 0; nt < 4; ++nt) {
                const int krow = nt * 16 + lo;
                const int rot  = krow & 7;
                bf16x8 k0 = *(const bf16x8*)&Ks[krow * 64 + ((quad + rot) & 7) * 8];
                bf16x8 k1 = *(const bf16x8*)&Ks[krow * 64 + ((quad + 4 + rot) & 7) * 8];
                f32x4 cc = (f32x4){0.f, 0.f, 0.f, 0.f};
                cc = __builtin_amdgcn_mfma_f32_16x16x32_bf16(aq0, k0, cc, 0, 0, 0);
                cc = __builtin_amdgcn_mfma_f32_16x16x32_bf16(aq1, k1, cc, 0, 0, 0);
                sc[nt] = cc;
            }

            if (kt == tile) {   // diagonal tile (only in the matching parity)
#pragma unroll
                for (int nt = 0; nt < 4; ++nt)
#pragma unroll
                    for (int r = 0; r < 4; ++r)
                        if (nt * 16 + lo > w * 16 + quad * 4 + r)
                            sc[nt][r] = -1e30f;
            }

#pragma unroll
            for (int nt = 0; nt < 4; ++nt) {
#pragma unroll
                for (int r = 0; r < 4; ++r) {
                    float pv = __expf(sc[nt][r]);
                    l_acc[r] += pv;
                    Ps[w][quad * 4 + r][nt * 16 + lo] = (__bf16)pv;
                }
            }
            bf16x8 ap0 = *(const bf16x8*)&Ps[w][lo][quad * 8];
            bf16x8 ap1 = *(const bf16x8*)&Ps[w][lo][32 + quad * 8];

#pragma unroll
            for (int dt = 0; dt < 4; ++dt) {
                const int vrow = dt * 16 + lo;
                const int vrot = vrow & 7;
                bf16x8 vb0 = *(const bf16x8*)&Vt[vrow * 64 + ((quad + vrot) & 7) * 8];
                bf16x8 vb1 = *(const bf16x8*)&Vt[vrow * 64 + ((quad + 4 + vrot) & 7) * 8];
                o_acc[dt] = __builtin_amdgcn_mfma_f32_16x16x32_bf16(ap0, vb0, o_acc[dt], 0, 0, 0);
                o_acc[dt] = __builtin_amdgcn_mfma_f32_16x16x32_bf16(ap1, vb1, o_acc[dt], 0, 0, 0);
            }
        }

        // --- epilogue: raw partial O (bf16) + partial l; no division ---
#pragma unroll
        for (int r = 0; r < 4; ++r) {
            float lr = l_acc[r];
            lr += __shfl_xor(lr, 1, 64);
            lr += __shfl_xor(lr, 2, 64);
            lr += __shfl_xor(lr, 4, 64);
            lr += __shfl_xor(lr, 8, 64);
            const int sq = qrow_w + quad * 4 + r;
            __bf16* orow = Opart + ((size_t)(hf * 32 + bh) * S_LEN + sq) * 64;
#pragma unroll
            for (int dt = 0; dt < 4; ++dt)
                orow[dt * 16 + lo] = (__bf16)o_acc[dt][r];
            if (lo == 0) lpart[(size_t)(hf * 32 + bh) * S_LEN + sq] = lr;
        }
    }
}

// ---------------------------------------------------------------------------
// combine: O = (O0+O1)/(l0+l1) per token; computes per-token sumsq (replaces
// attn atomics) and writes attnb in the rotated GEMM-A layout.
// One block per token; thread t -> head t>>4, dims (t*4)&63 .. +4.
// ---------------------------------------------------------------------------
__global__ __launch_bounds__(256) void combine(const __bf16* __restrict__ Opart,
                                               const float* __restrict__ lpart,
                                               __bf16* __restrict__ attnb,
                                               float* __restrict__ sumsq) {
    __shared__ float red[4];
    const int token = blockIdx.x;
    const int b = token & 1, s = token >> 1;
    const int t = threadIdx.x;
    const int h = t >> 4;
    const int d = (t * 4) & 63;
    const int bh = b * NH + h;

    size_t i0 = ((size_t)bh * S_LEN + s) * 64 + d;
    size_t i1 = ((size_t)(32 + bh) * S_LEN + s) * 64 + d;
    bf16x4 a0 = *(const bf16x4*)(Opart + i0);
    bf16x4 a1 = *(const bf16x4*)(Opart + i1);
    float l = lpart[(size_t)bh * S_LEN + s] + lpart[(size_t)(32 + bh) * S_LEN + s];
    float inv = 1.f / l;
    float o0 = ((float)a0[0] + (float)a1[0]) * inv;
    float o1 = ((float)a0[1] + (float)a1[1]) * inv;
    float o2 = ((float)a0[2] + (float)a1[2]) * inv;
    float o3 = ((float)a0[3] + (float)a1[3]) * inv;

    float ss = o0 * o0 + o1 * o1 + o2 * o2 + o3 * o3;
#pragma unroll
    for (int o = 32; o; o >>= 1) ss += __shfl_xor(ss, o, 64);
    if ((t & 63) == 0) red[t >> 6] = ss;
    __syncthreads();
    if (t == 0) sumsq[token] = red[0] + red[1] + red[2] + red[3];

    bf16x4 ov;
    ov[0] = (__bf16)o0; ov[1] = (__bf16)o1;
    ov[2] = (__bf16)o2; ov[3] = (__bf16)o3;
    const int c = t * 4;
    const int rot = (token & 7) * 8;
    const int cp = (c & ~63) | ((c + rot) & 63);
    *(bf16x4*)(attnb + (size_t)token * EDIM + cp) = ov;
}

// ---------------------------------------------------------------------------
extern "C" void kernel_launch(void* const* d_in, const int* in_sizes, int n_in,
                              void* d_out, int out_size, void* d_ws, size_t ws_size,
                              hipStream_t stream) {
    const float* x    = (const float*)d_in[0];
    const float* cosT = (const float*)d_in[2];
    const float* sinT = (const float*)d_in[3];
    const float* Wq   = (const float*)d_in[4];
    const float* bq   = (const float*)d_in[5];
    const float* Wk   = (const float*)d_in[6];
    const float* bk   = (const float*)d_in[7];
    const float* Wv   = (const float*)d_in[8];
    const float* bv   = (const float*)d_in[9];
    const float* Wo   = (const float*)d_in[10];
    const float* nw   = (const float*)d_in[11];
    float* out = (float*)d_out;

    // Workspace (80 MiB):
    //   [ 0, 8) qb bf16 [bh][s][64]
    //   [ 8,16) attnb bf16 [token][E] (rotated; written by combine)
    //   [16,17) sumsq fp32 [4096]
    //   [17,33) Opart bf16 [2][bh][s][64] (attn partials)
    //   [33,34) lpart fp32 [2][bh][s]
    //   [48,56) xb bf16 (rotated)
    //   [56,64) kb bf16 [bh][s][64] rot
    //   [64,72) vT bf16 [bh][d][s] rot
    //   [72,78) Wqkvb bf16 (rotated)
    //   [78,80) Wob bf16 (rotated, nw folded)
    char* wsb = (char*)d_ws;
    const size_t MB = 1024 * 1024;
    __bf16* qb     = (__bf16*)(wsb + 0 * MB);
    __bf16* attnb  = (__bf16*)(wsb + 8 * MB);
    float*  sumsq  = (float*)(wsb + 16 * MB);
    __bf16* Opart  = (__bf16*)(wsb + 17 * MB);
    float*  lpart  = (float*)(wsb + 33 * MB);
    __bf16* xb     = (__bf16*)(wsb + 48 * MB);
    __bf16* kb     = (__bf16*)(wsb + 56 * MB);
    __bf16* vT     = (__bf16*)(wsb + 64 * MB);
    __bf16* Wqkvb  = (__bf16*)(wsb + 72 * MB);
    __bf16* Wob    = (__bf16*)(wsb + 78 * MB);

    cast_all<<<(8 * 1024 * 1024) / (256 * 8), 256, 0, stream>>>(
        x, Wq, Wk, Wv, Wo, nw, xb, Wqkvb, Wob, sumsq);

    gemm_qkv<<<dim3(3072 / 128, MTOK / 128), 256, 0, stream>>>(
        xb, Wqkvb, bq, bk, bv, qb, kb, vT, cosT, sinT);

    // uniform-duration split-K attention: 32 bh x (16 pairs x 2 halves)
    attn_v7<<<dim3(BATCH * NH, 32), 256, 0, stream>>>(qb, kb, vT, Opart, lpart);

    combine<<<MTOK, 256, 0, stream>>>(Opart, lpart, attnb, sumsq);

    gemm_out<<<dim3(1024 / 128, MTOK / 128), 256, 0, stream>>>(
        attnb, Wob, sumsq, out);
}